// Round 2
// baseline (206.316 us; speedup 1.0000x reference)
//
#include <hip/hip_runtime.h>
#include <hip/hip_bf16.h>
#include <stdint.h>

// Problem: X = fm_t reshaped [N=1024, D=16384] fp32.
// loss = mean_{i,j} ((sq_i + sq_j - 2*g_ij)/D)^2,  g = X X^T, sq_i = |x_i|^2.
// G is symmetric: compute only upper-triangle 128x128 tiles (36 of 64),
// weight off-diagonal tiles x2 in the loss reduction.
#define N_ROWS 1024
#define KDIM   16384
#define SPLITK 16
#define KBLK   (KDIM / SPLITK)   // 1024 -> 16 k-iterations of 64 per block

typedef __attribute__((ext_vector_type(8))) __bf16 bf16x8;
typedef __attribute__((ext_vector_type(4))) float  f32x4;

#define GLOBAL_AS __attribute__((address_space(1)))
#define LDS_AS    __attribute__((address_space(3)))

// Upper-triangle tile enumeration: t -> (ti, tj), ti <= tj, 8x8 tile grid.
__device__ __constant__ unsigned char T_I[36] = {
    0,0,0,0,0,0,0,0, 1,1,1,1,1,1,1, 2,2,2,2,2,2, 3,3,3,3,3, 4,4,4,4, 5,5,5, 6,6, 7};
__device__ __constant__ unsigned char T_J[36] = {
    0,1,2,3,4,5,6,7, 1,2,3,4,5,6,7, 2,3,4,5,6,7, 3,4,5,6,7, 4,5,6,7, 5,6,7, 6,7, 7};

__device__ __forceinline__ unsigned short f32_to_bf16_rne(float f) {
    unsigned int u = __float_as_uint(f);
    unsigned int lsb = (u >> 16) & 1u;
    u += 0x7fffu + lsb;
    return (unsigned short)(u >> 16);
}

// Kernel 1: fused fp32->bf16 cast of X plus exact fp32 row norms sq[i].
// One block per row: 16384 floats = 4096 float4 = 16 float4/thread.
__global__ __launch_bounds__(256) void cast_sq_kernel(
        const float* __restrict__ X, unsigned short* __restrict__ Xb,
        float* __restrict__ sq) {
    const int row = blockIdx.x;
    const float4* src = (const float4*)(X + (size_t)row * KDIM);
    uint2* dst = (uint2*)(Xb + (size_t)row * KDIM);
    float ss = 0.f;
#pragma unroll
    for (int c = 0; c < 16; ++c) {
        int idx = c * 256 + threadIdx.x;
        float4 v = src[idx];
        ss += v.x * v.x + v.y * v.y + v.z * v.z + v.w * v.w;
        uint2 p;
        p.x = (unsigned int)f32_to_bf16_rne(v.x) | ((unsigned int)f32_to_bf16_rne(v.y) << 16);
        p.y = (unsigned int)f32_to_bf16_rne(v.z) | ((unsigned int)f32_to_bf16_rne(v.w) << 16);
        dst[idx] = p;
    }
#pragma unroll
    for (int o = 32; o; o >>= 1) ss += __shfl_down(ss, o, 64);
    __shared__ float red[4];
    int lane = threadIdx.x & 63, wv = threadIdx.x >> 6;
    if (lane == 0) red[wv] = ss;
    __syncthreads();
    if (threadIdx.x == 0) sq[row] = red[0] + red[1] + red[2] + red[3];
}

// Kernel 2: split-K bf16 Gram GEMM over upper-triangle tiles only.
// BM=BN=128, BK=64, 256 threads = 2x2 waves of 64x64 (4x4 16x16x32 frags).
// LDS XOR swizzle: row r's 16B k-chunk j lives at slot j ^ (r&7), so the 16
// lanes of each ds_read_b128 spread over all 32 banks (2-way = free, m136).
// Staging keeps the lane-linear LDS destination required by global_load_lds;
// the permutation is applied to the per-lane GLOBAL source address.
__global__ __launch_bounds__(256) void gram_gemm_kernel(
        const unsigned short* __restrict__ Xb, float* __restrict__ G) {
    __shared__ unsigned short As[128 * 64];  // 16 KB
    __shared__ unsigned short Bs[128 * 64];  // 16 KB

    const int ti = T_I[blockIdx.x];
    const int tj = T_J[blockIdx.x];
    const int row0 = ti * 128;
    const int col0 = tj * 128;
    const int kbeg = blockIdx.y * KBLK;
    const int kend = kbeg + KBLK;

    const int tid  = threadIdx.x;
    const int lane = tid & 63;
    const int wv   = tid >> 6;
    const int wm   = (wv >> 1) * 64;
    const int wn   = (wv & 1) * 64;
    const int lr   = lane & 15;
    const int lq   = lane >> 4;        // 0..3 (k sub-chunk selector)
    const int swz  = lr & 7;           // XOR key (row&7 within any 16-row group)

    f32x4 acc[4][4] = {};

    for (int k0 = kbeg; k0 < kend; k0 += 64) {
        // stage A,B: 1024 16B chunks each, lane-linear LDS dest, swizzled src
#pragma unroll
        for (int it = 0; it < 4; ++it) {
            int c  = it * 256 + tid;        // linear chunk id 0..1023
            int r  = c >> 3;                // tile row 0..127
            int j  = c & 7;                 // LDS slot within row
            int js = j ^ (r & 7);           // global k-chunk that fills slot j
            const unsigned short* ga = Xb + (size_t)(row0 + r) * KDIM + k0 + js * 8;
            const unsigned short* gb = Xb + (size_t)(col0 + r) * KDIM + k0 + js * 8;
            __builtin_amdgcn_global_load_lds((GLOBAL_AS void*)(void*)ga,
                                             (LDS_AS void*)&As[c * 8], 16, 0, 0);
            __builtin_amdgcn_global_load_lds((GLOBAL_AS void*)(void*)gb,
                                             (LDS_AS void*)&Bs[c * 8], 16, 0, 0);
        }
        __syncthreads();

#pragma unroll
        for (int s = 0; s < 2; ++s) {
            const int kch = s * 4 + lq;     // global 16B k-chunk 0..7
            const int slot = (kch ^ swz) * 8;
            bf16x8 af[4], bfq[4];
#pragma unroll
            for (int i = 0; i < 4; ++i)
                af[i] = *(const bf16x8*)&As[(wm + i * 16 + lr) * 64 + slot];
#pragma unroll
            for (int j = 0; j < 4; ++j)
                bfq[j] = *(const bf16x8*)&Bs[(wn + j * 16 + lr) * 64 + slot];
#pragma unroll
            for (int i = 0; i < 4; ++i)
#pragma unroll
                for (int j = 0; j < 4; ++j)
                    acc[i][j] = __builtin_amdgcn_mfma_f32_16x16x32_bf16(
                        af[i], bfq[j], acc[i][j], 0, 0, 0);
        }
        __syncthreads();
    }

    // epilogue: C/D layout col=lane&15, row=(lane>>4)*4+reg
    const int crow0 = row0 + wm + lq * 4;
    const int ccol0 = col0 + wn + lr;
#pragma unroll
    for (int i = 0; i < 4; ++i)
#pragma unroll
        for (int j = 0; j < 4; ++j)
#pragma unroll
            for (int r = 0; r < 4; ++r) {
                int grow = crow0 + i * 16 + r;
                int gcol = ccol0 + j * 16;
                atomicAdd(&G[(size_t)grow * N_ROWS + gcol], acc[i][j][r]);
            }
}

// Kernel 3: loss = (1/N^2) * sum over upper tiles of w * ((sq_i+sq_j-2g)/D)^2
// with w=1 on diagonal tiles (they contain both triangles) and w=2 off-diag.
__global__ __launch_bounds__(256) void loss_kernel(
        const float* __restrict__ G, const float* __restrict__ sq,
        float* __restrict__ out) {
    const float invD = 1.0f / (float)KDIM;
    const int TOT = 36 * 128 * 128;
    float acc = 0.f;
    for (int u = blockIdx.x * 256 + threadIdx.x; u < TOT; u += gridDim.x * 256) {
        int t = u >> 14;
        int e = u & 16383;
        int i = T_I[t] * 128 + (e >> 7);
        int j = T_J[t] * 128 + (e & 127);
        float g = G[i * N_ROWS + j];
        float v = (sq[i] + sq[j] - 2.0f * g) * invD;
        float w = (T_I[t] == T_J[t]) ? 1.0f : 2.0f;
        acc += w * v * v;
    }
#pragma unroll
    for (int o = 32; o; o >>= 1) acc += __shfl_down(acc, o, 64);
    __shared__ float red[4];
    int lane = threadIdx.x & 63, wv = threadIdx.x >> 6;
    if (lane == 0) red[wv] = acc;
    __syncthreads();
    if (threadIdx.x == 0) {
        float total = red[0] + red[1] + red[2] + red[3];
        atomicAdd(out, total * (1.0f / ((float)N_ROWS * (float)N_ROWS)));
    }
}

extern "C" void kernel_launch(void* const* d_in, const int* in_sizes, int n_in,
                              void* d_out, int out_size, void* d_ws, size_t ws_size,
                              hipStream_t stream) {
    // d_in[0] = fm_s (dead per reference bug), d_in[1] = fm_t
    const float* fm_t = (const float*)d_in[1];
    float* out = (float*)d_out;

    // Workspace: Xb bf16 [32 MB] | G fp32 [4 MB] | sq fp32 [4 KB]
    char* ws = (char*)d_ws;
    unsigned short* Xb = (unsigned short*)ws;
    float* G  = (float*)(ws + (size_t)N_ROWS * KDIM * 2);
    float* sq = (float*)(ws + (size_t)N_ROWS * KDIM * 2 + (size_t)N_ROWS * N_ROWS * 4);

    hipMemsetAsync(G, 0, (size_t)N_ROWS * N_ROWS * sizeof(float), stream);
    hipMemsetAsync(out, 0, sizeof(float), stream);

    cast_sq_kernel<<<dim3(N_ROWS), 256, 0, stream>>>(fm_t, Xb, sq);
    gram_gemm_kernel<<<dim3(36, SPLITK), 256, 0, stream>>>(Xb, G);
    loss_kernel<<<dim3(256), 256, 0, stream>>>(G, sq, out);
}